// Round 6
// baseline (63.452 us; speedup 1.0000x reference)
//
#include <hip/hip_runtime.h>
#include <hip/hip_fp16.h>
#include <math.h>

#define C_MAX 2000   // cameras; LDS table sized for this

typedef float f32x4 __attribute__((ext_vector_type(4)));

// ---------- helpers ----------
__device__ __forceinline__ unsigned pkh(float a, float b) {
    union { unsigned u; __half2 h; } x;
    x.h = __floats2half2_rn(a, b);
    return x.u;
}
__device__ __forceinline__ float2 uph(unsigned u) {
    union { unsigned u; __half2 h; } x;
    x.u = u;
    return make_float2(__low2float(x.h), __high2float(x.h));
}

__device__ __forceinline__ void quat_to_R(float q0, float q1, float q2, float q3, float R[9]) {
    float inv = 1.0f / sqrtf(q0 * q0 + q1 * q1 + q2 * q2 + q3 * q3);
    float x = q0 * inv, y = q1 * inv, z = q2 * inv, w = q3 * inv;
    R[0] = 1.0f - 2.0f * (y * y + z * z);
    R[1] = 2.0f * (x * y - w * z);
    R[2] = 2.0f * (x * z + w * y);
    R[3] = 2.0f * (x * y + w * z);
    R[4] = 1.0f - 2.0f * (x * x + z * z);
    R[5] = 2.0f * (y * z - w * x);
    R[6] = 2.0f * (x * z - w * y);
    R[7] = 2.0f * (y * z + w * x);
    R[8] = 1.0f - 2.0f * (x * x + y * y);
}

// ---------- per-camera precompute: compose pose, fold K, pack to 24B ----------
// cam4[c] = {pk(M00,M01), pk(M02,M10), pk(M11,M12), pk(M20,M21)}
// cam2[c] = {pk(M22,v0), pk(v1,v2)}
__global__ void cam_precompute(const float* __restrict__ base_poses,
                               const float* __restrict__ rel_poses,
                               const float* __restrict__ intr,
                               const int* __restrict__ lookup,
                               uint4* __restrict__ cam4,
                               uint2* __restrict__ cam2,
                               int C) {
    int c = blockIdx.x * blockDim.x + threadIdx.x;
    if (c >= C) return;
    int bpi = lookup[2 * c + 0];
    int rpi = lookup[2 * c + 1];
    bool has_rel = (rpi != -1);
    int rs = has_rel ? rpi : 0;

    const float* bp = base_poses + 7 * bpi;
    float tb0 = bp[0], tb1 = bp[1], tb2 = bp[2];
    float Rb[9];
    quat_to_R(bp[3], bp[4], bp[5], bp[6], Rb);

    const float* rp = rel_poses + 7 * rs;
    float Rr[9];
    quat_to_R(rp[3], rp[4], rp[5], rp[6], Rr);

    float Rf[9], tf0, tf1, tf2;
    if (has_rel) {
        #pragma unroll
        for (int i = 0; i < 3; ++i) {
            #pragma unroll
            for (int j = 0; j < 3; ++j) {
                Rf[3 * i + j] = Rb[3 * i + 0] * Rr[0 + j]
                              + Rb[3 * i + 1] * Rr[3 + j]
                              + Rb[3 * i + 2] * Rr[6 + j];
            }
        }
        tf0 = tb0 + Rb[0] * rp[0] + Rb[1] * rp[1] + Rb[2] * rp[2];
        tf1 = tb1 + Rb[3] * rp[0] + Rb[4] * rp[1] + Rb[5] * rp[2];
        tf2 = tb2 + Rb[6] * rp[0] + Rb[7] * rp[1] + Rb[8] * rp[2];
    } else {
        #pragma unroll
        for (int i = 0; i < 9; ++i) Rf[i] = Rb[i];
        tf0 = tb0; tf1 = tb1; tf2 = tb2;
    }

    const float* K = intr + 9 * c;
    float M[9], v[3];
    #pragma unroll
    for (int i = 0; i < 3; ++i) {
        #pragma unroll
        for (int j = 0; j < 3; ++j) {
            M[3 * i + j] = K[3 * i + 0] * Rf[0 + j]
                         + K[3 * i + 1] * Rf[3 + j]
                         + K[3 * i + 2] * Rf[6 + j];
        }
        v[i] = K[3 * i + 0] * tf0 + K[3 * i + 1] * tf1 + K[3 * i + 2] * tf2;
    }

    uint4 w0;
    uint2 w1;
    w0.x = pkh(M[0], M[1]);
    w0.y = pkh(M[2], M[3]);
    w0.z = pkh(M[4], M[5]);
    w0.w = pkh(M[6], M[7]);
    w1.x = pkh(M[8], v[0]);
    w1.y = pkh(v[1], v[2]);
    cam4[c] = w0;
    cam2[c] = w1;
}

// ---------- pack points to fp16: 8B/point -> 4MB array (L2-resident) ----------
__global__ void pack_points(const float* __restrict__ pts, uint2* __restrict__ ph, int P) {
    int i = blockIdx.x * blockDim.x + threadIdx.x;
    if (i < P) {
        float x = pts[3 * i + 0], y = pts[3 * i + 1], z = pts[3 * i + 2];
        uint2 q;
        q.x = pkh(x, y);
        q.y = pkh(z, 0.0f);
        ph[i] = q;
    }
}

// ---------- main kernel ----------
__device__ __forceinline__ float2 project_one(const uint4& A, const uint2& B,
                                              const uint2& q, float mx, float my) {
    float2 m01 = uph(A.x);
    float2 m23 = uph(A.y);
    float2 m45 = uph(A.z);
    float2 m67 = uph(A.w);
    float2 m8v0 = uph(B.x);
    float2 v12 = uph(B.y);
    float2 xy = uph(q.x);
    float2 zp = uph(q.y);
    float px = xy.x, py = xy.y, pz = zp.x;

    float jx = m01.x * px + m01.y * py + m23.x * pz + m8v0.y;
    float jy = m23.y * px + m45.x * py + m45.y * pz + v12.x;
    float jz = m67.x * px + m67.y * py + m8v0.x * pz + v12.y;
    float iz = 1.0f / jz;
    return make_float2(jx * iz - mx, jy * iz - my);
}

__launch_bounds__(1024, 8)
__global__ void residual_lds(const float4* __restrict__ obs,
                             const uint2* __restrict__ pts,
                             const uint4* __restrict__ cam4g,
                             const uint2* __restrict__ cam2g,
                             float4* __restrict__ out,
                             int G,   // ceil(N/4)
                             long N,  // total observations
                             int C) {
    __shared__ uint4 s4[C_MAX];   // 32 KB
    __shared__ uint2 s2[C_MAX];   // 16 KB  -> 48 KB total, 2 blocks/CU
    for (int i = threadIdx.x; i < C; i += blockDim.x) {
        s4[i] = cam4g[i];
        s2[i] = cam2g[i];
    }
    __syncthreads();

    const f32x4* obsv = (const f32x4*)obs;
    int stride = gridDim.x * blockDim.x;
    for (int g = blockIdx.x * blockDim.x + threadIdx.x; g < G; g += stride) {
        long base = (long)g * 4;
        if (base + 3 < N) {
            // non-temporal stream loads: obs is read exactly once
            f32x4 o0 = __builtin_nontemporal_load(&obsv[base + 0]);
            f32x4 o1 = __builtin_nontemporal_load(&obsv[base + 1]);
            f32x4 o2 = __builtin_nontemporal_load(&obsv[base + 2]);
            f32x4 o3 = __builtin_nontemporal_load(&obsv[base + 3]);

            int c0 = (int)o0.x, p0 = (int)o0.y;
            int c1 = (int)o1.x, p1 = (int)o1.y;
            int c2 = (int)o2.x, p2 = (int)o2.y;
            int c3 = (int)o3.x, p3 = (int)o3.y;

            // independent global gathers first (8B each, L2-resident array)
            uint2 q0 = pts[p0], q1 = pts[p1], q2 = pts[p2], q3 = pts[p3];

            // LDS camera reads (b128 + b64 each, naturally aligned SoA)
            uint4 A0 = s4[c0], A1 = s4[c1], A2 = s4[c2], A3 = s4[c3];
            uint2 B0 = s2[c0], B1 = s2[c1], B2 = s2[c2], B3 = s2[c3];

            float2 r0 = project_one(A0, B0, q0, o0.z, o0.w);
            float2 r1 = project_one(A1, B1, q1, o1.z, o1.w);
            float2 r2 = project_one(A2, B2, q2, o2.z, o2.w);
            float2 r3 = project_one(A3, B3, q3, o3.z, o3.w);

            f32x4 r01 = {r0.x, r0.y, r1.x, r1.y};
            f32x4 r23 = {r2.x, r2.y, r3.x, r3.y};
            f32x4* outv = (f32x4*)out;
            __builtin_nontemporal_store(r01, &outv[2 * g + 0]);
            __builtin_nontemporal_store(r23, &outv[2 * g + 1]);
        } else {
            float2* out2 = (float2*)out;
            for (long i = base; i < N; ++i) {
                float4 o = obs[i];
                int cam = (int)o.x;
                int pt = (int)o.y;
                uint4 A = s4[cam];
                uint2 B = s2[cam];
                uint2 q = pts[pt];
                float2 r = project_one(A, B, q, o.z, o.w);
                out2[i] = r;
            }
        }
    }
}

extern "C" void kernel_launch(void* const* d_in, const int* in_sizes, int n_in,
                              void* d_out, int out_size, void* d_ws, size_t ws_size,
                              hipStream_t stream) {
    const float* obs = (const float*)d_in[0];
    const float* base_poses = (const float*)d_in[1];
    const float* rel_poses = (const float*)d_in[2];
    const float* points = (const float*)d_in[3];
    const float* intr = (const float*)d_in[4];
    const int* lookup = (const int*)d_in[5];

    long N = in_sizes[0] / 4;   // observations
    int P = in_sizes[3] / 3;    // points
    int C = in_sizes[5] / 2;    // cameras

    // ws layout: [0,32K) cam4 ; [32K,48K) cam2 ; [48K, 48K+8P) fp16 points
    uint4* cam4 = (uint4*)d_ws;
    uint2* cam2 = (uint2*)((char*)d_ws + (size_t)C_MAX * 16);
    uint2* pts_h = (uint2*)((char*)d_ws + (size_t)C_MAX * 24);

    cam_precompute<<<(C + 255) / 256, 256, 0, stream>>>(
        base_poses, rel_poses, intr, lookup, cam4, cam2, C);
    pack_points<<<(P + 255) / 256, 256, 0, stream>>>(points, pts_h, P);

    int G = (int)((N + 3) / 4);
    int threads = 1024;
    int blocks = 512;   // 2 blocks/CU (48KB LDS each) -> 32 waves/CU
    residual_lds<<<blocks, threads, 0, stream>>>(
        (const float4*)obs, pts_h, cam4, cam2, (float4*)d_out, G, N, C);
}